// Round 2
// baseline (602.510 us; speedup 1.0000x reference)
//
#include <hip/hip_runtime.h>
#include <hip/hip_bf16.h>

typedef __bf16 bf16_t;
typedef __bf16 bf16x8 __attribute__((ext_vector_type(8)));
typedef float f32x4 __attribute__((ext_vector_type(4)));

#define LOG2E 1.44269504088896340736f
#define LN2 0.69314718055994530942f

__device__ __forceinline__ float fast_exp2(float x) { return __builtin_amdgcn_exp2f(x); }
__device__ __forceinline__ float fast_log2(float x) { return __builtin_amdgcn_logf(x); }
__device__ __forceinline__ float fast_rcp(float x) { return __builtin_amdgcn_rcpf(x); }

__device__ __forceinline__ float softplus_f(float x) {
    float sp = LN2 * fast_log2(1.0f + fast_exp2(x * LOG2E));
    return (x > 20.0f) ? x : sp;
}
// tanh(x) = 1 - 2/(1+e^{2x}); saturates correctly at both ends
__device__ __forceinline__ float tanh_f(float x) {
    float e = fast_exp2(x * (2.0f * LOG2E));
    return 1.0f - 2.0f * fast_rcp(1.0f + e);
}

template <int CTRL>
__device__ __forceinline__ float dpp_add(float v) {
    int iv = __builtin_bit_cast(int, v);
    int sv = __builtin_amdgcn_update_dpp(0, iv, CTRL, 0xF, 0xF, true);
    return v + __builtin_bit_cast(float, sv);
}

// B=4096, L=64, C=7, H=32, K=2 -> 126 RK4 steps, h=0.5
// Block: 1024 threads (16 waves), owns 16 batch rows. Grid: 256 blocks.
// Per stage: 2 barriers. Phase A: GEMV1 (+dxs). Phase B: GEMV2 + z-update in regs.
__global__ __launch_bounds__(1024, 4) void cde_kernel(
    const float* __restrict__ x,    // (4096,64,7)
    const float* __restrict__ Wi,   // (32,7)
    const float* __restrict__ bi,   // (32,)
    const float* __restrict__ W1,   // (32,32)
    const float* __restrict__ b1,   // (32,)
    const float* __restrict__ W2,   // (224,32)
    const float* __restrict__ b2,   // (224,)
    const float* __restrict__ Wo1,  // (16,32)
    const float* __restrict__ bo1,  // (16,)
    const float* __restrict__ Wo2,  // (3,16)
    const float* __restrict__ bo2,  // (3,)
    float* __restrict__ out)        // (4096,3)
{
    __shared__ float diffs[16][441];          // [r][i*7+c]
    __shared__ float dxs[16][9];              // pad 9 -> conflict-free col reads; [.][7]=0
    __shared__ bf16_t zhi[4][16][8], zlo[4][16][8];   // [k-chunk][row][pos] -> A-read is addr=16*lane
    __shared__ bf16_t h1hi[4][16][8], h1lo[4][16][8];
    __shared__ float zfin[16][32];
    __shared__ float wo1t[32][16];
    __shared__ float ubuf[16][16];

    const int tid = threadIdx.x;
    const int l = tid & 63;
    const int w = tid >> 6;          // wave 0..15
    const int r0 = blockIdx.x * 16;

    const int ar = l & 15;           // MFMA row (A) / col (B,C)
    const int chunk = l >> 4;        // k-chunk 0..3
    const int ak = chunk * 8;
    const int crow = chunk * 4;      // C/D row base

    // --- GEMV1 assignment: wave pair (w>>1) -> (tile,reg); w&1 -> crow half
    const int p1 = w >> 1;
    const int T1 = p1 >> 2;          // 0..1
    const int reg1 = p1 & 3;
    const bool hfsel = ((l >> 5) & 1) == (w & 1);
    const int h1col = 16 * T1 + ar;
    const int h1chunk = h1col >> 3, h1pos = h1col & 7;

    // --- GEMV2 assignment: wave w -> padded tile w (cols 16w..16w+15)
    const int N2 = 16 * w + ar;      // padded col; h = N2>>3, c = N2&7
    const int hcol2 = N2 >> 3;
    const int ccol2 = N2 & 7;
    const int hiown = (l >> 3) & 1;
    const int hown = 2 * w + hiown;  // h-col owned by this 8-lane group
    const int zchunk = hown >> 3, zpos = hown & 7;
    const bool isown = (l & 7) == 0;

    // ---- weight fragments (hi/lo bf16 split for ~f32 precision) ----
    bf16x8 w1h, w1l;
    {
        const float* p = &W1[(16 * T1 + ar) * 32 + ak];
#pragma unroll
        for (int j = 0; j < 8; ++j) {
            float v = p[j];
            bf16_t hh = (bf16_t)v;
            w1h[j] = hh;
            w1l[j] = (bf16_t)(v - (float)hh);
        }
    }
    const float b1c = b1[16 * T1 + ar];

    bf16x8 w2h, w2l;
    float b2c;
    if (ccol2 < 7) {
        const float* p = &W2[(hcol2 * 7 + ccol2) * 32 + ak];
#pragma unroll
        for (int j = 0; j < 8; ++j) {
            float v = p[j];
            bf16_t hh = (bf16_t)v;
            w2h[j] = hh;
            w2l[j] = (bf16_t)(v - (float)hh);
        }
        b2c = b2[hcol2 * 7 + ccol2];
    } else {
#pragma unroll
        for (int j = 0; j < 8; ++j) { w2h[j] = (bf16_t)0.0f; w2l[j] = (bf16_t)0.0f; }
        b2c = 0.0f;
    }

    // ---- spline diffs into LDS ----
    for (int e = tid; e < 16 * 441; e += 1024) {
        int r = e / 441, rem = e - r * 441;
        const float* px = &x[(size_t)(r0 + r) * 448];
        diffs[r][rem] = px[rem + 7] - px[rem];
    }
    // ---- z0 = x[:,0] @ Wi^T + bi ----
    if (tid < 512) {
        int r = tid >> 5, hh = tid & 31;
        const float* px = &x[(size_t)(r0 + r) * 448];
        float acc = bi[hh];
#pragma unroll
        for (int c = 0; c < 7; ++c) acc += px[c] * Wi[hh * 7 + c];
        zfin[r][hh] = acc;
        bf16_t zh = (bf16_t)acc;
        zhi[hh >> 3][r][hh & 7] = zh;
        zlo[hh >> 3][r][hh & 7] = (bf16_t)(acc - (float)zh);
    }
    if (l == 7) dxs[w][7] = 0.0f;    // padded-c column contributes 0
    __syncthreads();

    // owner-register RK4 state (valid per 8-lane group; identical within group)
    float zb[4], ka[4];
#pragma unroll
    for (int rr = 0; rr < 4; ++rr) { zb[rr] = zfin[crow + rr][hown]; ka[rr] = 0.0f; }

    for (int k = 0; k < 126; ++k) {
#pragma unroll
        for (int s = 0; s < 4; ++s) {
            // ---------- phase A: dxs + GEMV1 ----------
            if (s != 2 && l < 7) {     // wave w computes row w; k2,k3 share t+h/2
                int m = 2 * k + (s == 0 ? 0 : (s == 3 ? 2 : 1));   // t = 0.25*m
                int i = m >> 2; if (i > 62) i = 62;
                float f = 0.25f * (float)(m - 4 * i);
                float D = diffs[w][i * 7 + l];
                float a = diffs[w][(i > 0 ? i - 1 : 0) * 7 + l];
                dxs[w][l] = a + (D - a) * (f * (4.0f - 3.0f * f));
            }
            {
                bf16x8 azh = *(const bf16x8*)&zhi[chunk][ar][0];
                bf16x8 azl = *(const bf16x8*)&zlo[chunk][ar][0];
                f32x4 d1 = {b1c, b1c, b1c, b1c};
                d1 = __builtin_amdgcn_mfma_f32_16x16x32_bf16(azh, w1h, d1, 0, 0, 0);
                d1 = __builtin_amdgcn_mfma_f32_16x16x32_bf16(azl, w1h, d1, 0, 0, 0);
                d1 = __builtin_amdgcn_mfma_f32_16x16x32_bf16(azh, w1l, d1, 0, 0, 0);
                if (hfsel) {
                    float sp = softplus_f(d1[reg1]);
                    bf16_t sh = (bf16_t)sp;
                    h1hi[h1chunk][crow + reg1][h1pos] = sh;
                    h1lo[h1chunk][crow + reg1][h1pos] = (bf16_t)(sp - (float)sh);
                }
            }
            __syncthreads();
            // ---------- phase B: GEMV2 + tanh + reduce + z-update ----------
            {
                bf16x8 ahh = *(const bf16x8*)&h1hi[chunk][ar][0];
                bf16x8 ahl = *(const bf16x8*)&h1lo[chunk][ar][0];
                f32x4 d2 = {b2c, b2c, b2c, b2c};
                d2 = __builtin_amdgcn_mfma_f32_16x16x32_bf16(ahh, w2h, d2, 0, 0, 0);
                d2 = __builtin_amdgcn_mfma_f32_16x16x32_bf16(ahl, w2h, d2, 0, 0, 0);
                d2 = __builtin_amdgcn_mfma_f32_16x16x32_bf16(ahh, w2l, d2, 0, 0, 0);
#pragma unroll
                for (int rr = 0; rr < 4; ++rr) {
                    float g = tanh_f(d2[rr]);
                    float v = g * dxs[crow + rr][ccol2];
                    v = dpp_add<0xB1>(v);    // + lane^1
                    v = dpp_add<0x4E>(v);    // + lane^2
                    v = dpp_add<0x141>(v);   // + mirrored half-row -> full 8-group sum
                    float zs;
                    if (s == 0)      { ka[rr] = v;          zs = zb[rr] + 0.25f * v; }
                    else if (s == 1) { ka[rr] += 2.0f * v;  zs = zb[rr] + 0.25f * v; }
                    else if (s == 2) { ka[rr] += 2.0f * v;  zs = zb[rr] + 0.5f * v; }
                    else             { zb[rr] += (1.0f / 12.0f) * (ka[rr] + v); zs = zb[rr]; }
                    bf16_t zh = (bf16_t)zs;
                    if (isown) {
                        zhi[zchunk][crow + rr][zpos] = zh;
                        zlo[zchunk][crow + rr][zpos] = (bf16_t)(zs - (float)zh);
                    }
                }
            }
            __syncthreads();
        }
    }

    // ---- epilogue: out = softplus(z @ Wo1^T + bo1) @ Wo2^T + bo2 ----
#pragma unroll
    for (int rr = 0; rr < 4; ++rr)
        if (isown) zfin[crow + rr][hown] = zb[rr];
    if (tid < 512) {
        int hh = tid >> 4, jj = tid & 15;
        wo1t[hh][jj] = Wo1[jj * 32 + hh];
    }
    __syncthreads();
    if (tid < 256) {
        int r = tid >> 4, jj = tid & 15;
        float acc = bo1[jj];
#pragma unroll
        for (int hh = 0; hh < 32; ++hh) acc += zfin[r][hh] * wo1t[hh][jj];
        ubuf[r][jj] = softplus_f(acc);
    }
    __syncthreads();
    if (tid < 48) {
        int r = tid / 3, o = tid - (tid / 3) * 3;
        float acc = bo2[o];
#pragma unroll
        for (int j = 0; j < 16; ++j) acc += ubuf[r][j] * Wo2[o * 16 + j];
        out[(size_t)(r0 + r) * 3 + o] = acc;
    }
}

extern "C" void kernel_launch(void* const* d_in, const int* in_sizes, int n_in,
                              void* d_out, int out_size, void* d_ws, size_t ws_size,
                              hipStream_t stream) {
    (void)in_sizes; (void)n_in; (void)d_ws; (void)ws_size; (void)out_size;
    const float* x   = (const float*)d_in[0];
    const float* Wi  = (const float*)d_in[1];
    const float* bi  = (const float*)d_in[2];
    const float* W1  = (const float*)d_in[3];
    const float* b1  = (const float*)d_in[4];
    const float* W2  = (const float*)d_in[5];
    const float* b2  = (const float*)d_in[6];
    const float* Wo1 = (const float*)d_in[7];
    const float* bo1 = (const float*)d_in[8];
    const float* Wo2 = (const float*)d_in[9];
    const float* bo2 = (const float*)d_in[10];
    cde_kernel<<<dim3(256), dim3(1024), 0, stream>>>(x, Wi, bi, W1, b1, W2, b2,
                                                     Wo1, bo1, Wo2, bo2, (float*)d_out);
}

// Round 4
// 467.996 us; speedup vs baseline: 1.2874x; 1.2874x over previous
//
#include <hip/hip_runtime.h>
#include <hip/hip_bf16.h>

typedef __bf16 bf16_t;
typedef __bf16 bf16x8 __attribute__((ext_vector_type(8)));
typedef float f32x4 __attribute__((ext_vector_type(4)));

#define LOG2E 1.44269504088896340736f
#define LN2 0.69314718055994530942f

__device__ __forceinline__ float fast_exp2(float x) { return __builtin_amdgcn_exp2f(x); }
__device__ __forceinline__ float fast_log2(float x) { return __builtin_amdgcn_logf(x); }
__device__ __forceinline__ float fast_rcp(float x) { return __builtin_amdgcn_rcpf(x); }

__device__ __forceinline__ float softplus_f(float x) {
    float sp = LN2 * fast_log2(1.0f + fast_exp2(x * LOG2E));
    return (x > 20.0f) ? x : sp;
}
// tanh(x) = 1 - 2/(1+e^{2x}); saturates correctly at both ends
__device__ __forceinline__ float tanh_f(float x) {
    float e = fast_exp2(x * (2.0f * LOG2E));
    return 1.0f - 2.0f * fast_rcp(1.0f + e);
}

template <int CTRL>
__device__ __forceinline__ float dpp_add(float v) {
    int iv = __builtin_bit_cast(int, v);
    int sv = __builtin_amdgcn_update_dpp(0, iv, CTRL, 0xF, 0xF, true);
    return v + __builtin_bit_cast(float, sv);
}
// full 8-lane-group sum, result in ALL 8 lanes
__device__ __forceinline__ float red8(float v) {
    v = dpp_add<0xB1>(v);   // + lane^1 (quad_perm [1,0,3,2])
    v = dpp_add<0x4E>(v);   // + lane^2 (quad_perm [2,3,0,1])
    v = dpp_add<0x141>(v);  // + mirrored half-row
    return v;
}

// B=4096, L=64, C=7, H=32, K=2 -> 126 RK4 steps, h=0.5
// Block: 512 threads (8 waves), owns 16 batch rows. Grid: 256 blocks.
// 2 barriers/stage. Phase A: dxs + GEMV1 (1 tile/wave, 1 softplus/lane).
// Phase B: GEMV2 (2 tiles/wave) + tanh + 8-lane reduce + duty-lane RK4 update.
__global__ __launch_bounds__(512) void cde_kernel(
    const float* __restrict__ x,    // (4096,64,7)
    const float* __restrict__ Wi,   // (32,7)
    const float* __restrict__ bi,   // (32,)
    const float* __restrict__ W1,   // (32,32)
    const float* __restrict__ b1,   // (32,)
    const float* __restrict__ W2,   // (224,32)
    const float* __restrict__ b2,   // (224,)
    const float* __restrict__ Wo1,  // (16,32)
    const float* __restrict__ bo1,  // (16,)
    const float* __restrict__ Wo2,  // (3,16)
    const float* __restrict__ bo2,  // (3,)
    float* __restrict__ out)        // (4096,3)
{
    __shared__ float diffs[16][441];                  // [r][i*7+c]
    __shared__ float dxs[16][9];                      // [r][c], [.][7]=0 pad
    __shared__ bf16_t zhi[4][16][8], zlo[4][16][8];   // [kchunk][row][kpos]
    __shared__ bf16_t h1hi[4][16][8], h1lo[4][16][8];
    __shared__ float zfin[16][32];
    __shared__ float wo1t[32][16];
    __shared__ float ubuf[16][16];

    const int tid = threadIdx.x;
    const int l = tid & 63;
    const int w = tid >> 6;          // wave 0..7
    const int r0 = blockIdx.x * 16;

    const int ar = l & 15;           // MFMA A-row / B-col / C-col
    const int chunk = l >> 4;        // k-chunk 0..3
    const int ak = chunk * 8;
    const int crow = chunk * 4;      // C/D row base

    // Phase-A duty: wave w -> (tile T1, C-reg reg1); every lane does 1 softplus
    const int T1 = w >> 2, reg1 = w & 3;
    const int h1col = 16 * T1 + ar;

    // Phase-B duty-lane mapping: lane owns (drow, dcol) RK4 state
    const int group = l >> 3;        // 8-lane reduce group (group>>1 == chunk)
    const int g = l & 7;             // position in group; also = c column
    const int dT = g >> 2, drr = g & 3;
    const int dcol = 4 * w + 2 * dT + (group & 1);
    const int drow = crow + drr;
    const bool selb0 = (drr & 1) != 0;
    const bool selb1 = (drr & 2) != 0;
    const bool selbT = dT != 0;

    // ---- weight fragments (hi/lo bf16 split for ~f32 precision) ----
    bf16x8 w1h, w1l;   // tile T1 only
    {
        const float* p = &W1[h1col * 32 + ak];
#pragma unroll
        for (int j = 0; j < 8; ++j) {
            float v = p[j];
            bf16_t hh = (bf16_t)v;
            w1h[j] = hh;
            w1l[j] = (bf16_t)(v - (float)hh);
        }
    }
    const float b1c = b1[h1col];

    bf16x8 w2h[2], w2l[2];
    float b2c[2];
#pragma unroll
    for (int T = 0; T < 2; ++T) {
        int N = 32 * w + 16 * T + ar;     // padded col; h=N>>3, c=N&7
        int hcol = N >> 3, ccol = N & 7;
        if (ccol < 7) {
            const float* p = &W2[(hcol * 7 + ccol) * 32 + ak];
#pragma unroll
            for (int j = 0; j < 8; ++j) {
                float v = p[j];
                bf16_t hh = (bf16_t)v;
                w2h[T][j] = hh;
                w2l[T][j] = (bf16_t)(v - (float)hh);
            }
            b2c[T] = b2[hcol * 7 + ccol];
        } else {
#pragma unroll
            for (int j = 0; j < 8; ++j) { w2h[T][j] = (bf16_t)0.0f; w2l[T][j] = (bf16_t)0.0f; }
            b2c[T] = 0.0f;
        }
    }

    // ---- spline diffs into LDS ----
    for (int e = tid; e < 16 * 441; e += 512) {
        int r = e / 441, rem = e - r * 441;
        const float* px = &x[(size_t)(r0 + r) * 448];
        diffs[r][rem] = px[rem + 7] - px[rem];
    }
    // ---- z0 = x[:,0] @ Wi^T + bi ----
    {
        int r = tid >> 5, hh = tid & 31;
        const float* px = &x[(size_t)(r0 + r) * 448];
        float acc = bi[hh];
#pragma unroll
        for (int c = 0; c < 7; ++c) acc += px[c] * Wi[hh * 7 + c];
        zfin[r][hh] = acc;
        bf16_t zh = (bf16_t)acc;
        zhi[hh >> 3][r][hh & 7] = zh;
        zlo[hh >> 3][r][hh & 7] = (bf16_t)(acc - (float)zh);
    }
    if (tid < 16) dxs[tid][7] = 0.0f;    // padded-c column contributes 0
    __syncthreads();

    // duty-lane RK4 state
    float zb = zfin[drow][dcol];
    float ka = 0.0f;

    for (int k = 0; k < 126; ++k) {
#pragma unroll
        for (int s = 0; s < 4; ++s) {
            // ---------- phase A: dxs (rows w, w+8) + GEMV1 ----------
            if (s != 2) {      // k2,k3 share t+h/2
                int rdx = -1, cdx = 0;
                if (l < 7) { rdx = w; cdx = l; }
                else if (l >= 32 && l < 39) { rdx = w + 8; cdx = l - 32; }
                if (rdx >= 0) {
                    int m = 2 * k + (s == 0 ? 0 : (s == 3 ? 2 : 1));   // t = 0.25*m
                    int i = m >> 2; if (i > 62) i = 62;
                    float f = 0.25f * (float)(m - 4 * i);
                    float D = diffs[rdx][i * 7 + cdx];
                    float a = diffs[rdx][(i > 0 ? i - 1 : 0) * 7 + cdx];
                    dxs[rdx][cdx] = a + (D - a) * (f * (4.0f - 3.0f * f));
                }
            }
            {
                bf16x8 azh = *(const bf16x8*)&zhi[chunk][ar][0];
                bf16x8 azl = *(const bf16x8*)&zlo[chunk][ar][0];
                f32x4 d1 = {b1c, b1c, b1c, b1c};
                d1 = __builtin_amdgcn_mfma_f32_16x16x32_bf16(azh, w1h, d1, 0, 0, 0);
                d1 = __builtin_amdgcn_mfma_f32_16x16x32_bf16(azl, w1h, d1, 0, 0, 0);
                d1 = __builtin_amdgcn_mfma_f32_16x16x32_bf16(azh, w1l, d1, 0, 0, 0);
                float sp = softplus_f(d1[reg1]);
                bf16_t sh = (bf16_t)sp;
                h1hi[h1col >> 3][crow + reg1][h1col & 7] = sh;
                h1lo[h1col >> 3][crow + reg1][h1col & 7] = (bf16_t)(sp - (float)sh);
            }
            __syncthreads();
            // ---------- phase B: GEMV2 + tanh + reduce + duty RK4 ----------
            {
                bf16x8 ahh = *(const bf16x8*)&h1hi[chunk][ar][0];
                bf16x8 ahl = *(const bf16x8*)&h1lo[chunk][ar][0];
                float dx0 = dxs[crow + 0][g];
                float dx1 = dxs[crow + 1][g];
                float dx2 = dxs[crow + 2][g];
                float dx3 = dxs[crow + 3][g];
                float vsel0, vsel1;
#pragma unroll
                for (int T = 0; T < 2; ++T) {
                    f32x4 d2 = {b2c[T], b2c[T], b2c[T], b2c[T]};
                    d2 = __builtin_amdgcn_mfma_f32_16x16x32_bf16(ahh, w2h[T], d2, 0, 0, 0);
                    d2 = __builtin_amdgcn_mfma_f32_16x16x32_bf16(ahl, w2h[T], d2, 0, 0, 0);
                    d2 = __builtin_amdgcn_mfma_f32_16x16x32_bf16(ahh, w2l[T], d2, 0, 0, 0);
                    float vr0 = red8(tanh_f(d2[0]) * dx0);
                    float vr1 = red8(tanh_f(d2[1]) * dx1);
                    float vr2 = red8(tanh_f(d2[2]) * dx2);
                    float vr3 = red8(tanh_f(d2[3]) * dx3);
                    float t01 = selb0 ? vr1 : vr0;
                    float t23 = selb0 ? vr3 : vr2;
                    float ts = selb1 ? t23 : t01;
                    if (T == 0) vsel0 = ts; else vsel1 = ts;
                }
                float v = selbT ? vsel1 : vsel0;
                float zs;
                if (s == 0)      { ka = v;           zs = zb + 0.25f * v; }
                else if (s == 1) { ka += 2.0f * v;   zs = zb + 0.25f * v; }
                else if (s == 2) { ka += 2.0f * v;   zs = zb + 0.5f * v; }
                else             { zb += (1.0f / 12.0f) * (ka + v); zs = zb; }
                bf16_t zh = (bf16_t)zs;
                zhi[dcol >> 3][drow][dcol & 7] = zh;
                zlo[dcol >> 3][drow][dcol & 7] = (bf16_t)(zs - (float)zh);
            }
            __syncthreads();
        }
    }

    // ---- epilogue: out = softplus(z @ Wo1^T + bo1) @ Wo2^T + bo2 ----
    zfin[drow][dcol] = zb;
    {
        int hh = tid >> 4, jj = tid & 15;
        wo1t[hh][jj] = Wo1[jj * 32 + hh];
    }
    __syncthreads();
    if (tid < 256) {
        int r = tid >> 4, jj = tid & 15;
        float acc = bo1[jj];
#pragma unroll
        for (int hh = 0; hh < 32; ++hh) acc += zfin[r][hh] * wo1t[hh][jj];
        ubuf[r][jj] = softplus_f(acc);
    }
    __syncthreads();
    if (tid < 48) {
        int r = tid / 3, o = tid - (tid / 3) * 3;
        float acc = bo2[o];
#pragma unroll
        for (int j = 0; j < 16; ++j) acc += ubuf[r][j] * Wo2[o * 16 + j];
        out[(size_t)(r0 + r) * 3 + o] = acc;
    }
}

extern "C" void kernel_launch(void* const* d_in, const int* in_sizes, int n_in,
                              void* d_out, int out_size, void* d_ws, size_t ws_size,
                              hipStream_t stream) {
    (void)in_sizes; (void)n_in; (void)d_ws; (void)ws_size; (void)out_size;
    const float* x   = (const float*)d_in[0];
    const float* Wi  = (const float*)d_in[1];
    const float* bi  = (const float*)d_in[2];
    const float* W1  = (const float*)d_in[3];
    const float* b1  = (const float*)d_in[4];
    const float* W2  = (const float*)d_in[5];
    const float* b2  = (const float*)d_in[6];
    const float* Wo1 = (const float*)d_in[7];
    const float* bo1 = (const float*)d_in[8];
    const float* Wo2 = (const float*)d_in[9];
    const float* bo2 = (const float*)d_in[10];
    cde_kernel<<<dim3(256), dim3(512), 0, stream>>>(x, Wi, bi, W1, b1, W2, b2,
                                                    Wo1, bo1, Wo2, bo2, (float*)d_out);
}